// Round 8
// baseline (518.308 us; speedup 1.0000x reference)
//
#include <hip/hip_runtime.h>
#include <hip/hip_bf16.h>

#define BATCH 256
#define NDIM  4096
#define STEPS 16
#define EPS_RMS 1.1920929e-07f

typedef _Float16 f16x8 __attribute__((ext_vector_type(8)));
typedef float  f32x4  __attribute__((ext_vector_type(4)));
typedef unsigned short u16x4 __attribute__((ext_vector_type(4)));
typedef unsigned short u16x8 __attribute__((ext_vector_type(8)));
typedef unsigned int   u32x4 __attribute__((ext_vector_type(4)));

#define AS1 __attribute__((address_space(1)))
#define AS3 __attribute__((address_space(3)))
#define GLDS16(gp, lp) __builtin_amdgcn_global_load_lds( \
    (const AS1 void*)(gp), (AS3 void*)(lp), 16, 0, 0)
#define SBAR() do { asm volatile("" ::: "memory"); \
                    __builtin_amdgcn_s_barrier();  \
                    asm volatile("" ::: "memory"); } while (0)

__device__ __forceinline__ unsigned short f2h(float f) {
  _Float16 h = (_Float16)f;
  union { _Float16 h; unsigned short u; } v; v.h = h; return v.u;
}
__device__ __forceinline__ float h2f(unsigned short u) {
  union { unsigned short u; _Float16 h; } v; v.u = u; return (float)v.h;
}

__device__ __forceinline__ float block_reduce_sum_512(float v) {
  __shared__ float ws[8];
  __shared__ float tot;
  #pragma unroll
  for (int off = 32; off > 0; off >>= 1) v += __shfl_down(v, off, 64);
  int lane = threadIdx.x & 63, w = threadIdx.x >> 6;
  if (lane == 0) ws[w] = v;
  __syncthreads();
  if (threadIdx.x == 0) {
    float t = 0.f;
    #pragma unroll
    for (int i = 0; i < 8; ++i) t += ws[i];
    tot = t;
  }
  __syncthreads();
  return tot;
}

// ---------------- W (f32, [k][n]) -> Wt (fp16, [n][k]) ----------------
__global__ __launch_bounds__(256) void transpose_w(
    const float* __restrict__ W, unsigned short* __restrict__ Wt) {
  __shared__ float tile[64][65];
  int n0 = blockIdx.x * 64;
  int k0 = blockIdx.y * 64;
  int t = threadIdx.x;
  int r = t >> 4, c4 = (t & 15) * 4;
  #pragma unroll
  for (int p = 0; p < 4; ++p) {
    f32x4 v = *(const f32x4*)(W + (size_t)(k0 + r + 16 * p) * NDIM + n0 + c4);
    tile[r + 16 * p][c4 + 0] = v[0];
    tile[r + 16 * p][c4 + 1] = v[1];
    tile[r + 16 * p][c4 + 2] = v[2];
    tile[r + 16 * p][c4 + 3] = v[3];
  }
  __syncthreads();
  #pragma unroll
  for (int p = 0; p < 4; ++p) {
    int nr = r + 16 * p;
    u16x4 o;
    #pragma unroll
    for (int j = 0; j < 4; ++j) o[j] = f2h(tile[c4 + j][nr]);
    *(u16x4*)(Wt + (size_t)(n0 + nr) * NDIM + k0 + c4) = o;
  }
}

// ---------------- column multipliers from scatter positions ----------------
__global__ void init_colmul(const float* __restrict__ iscale,
                            const float* __restrict__ oscale,
                            const int* __restrict__ ipos, const int* __restrict__ opos,
                            float* __restrict__ icm, float* __restrict__ ocm) {
  int c = blockIdx.x * 256 + threadIdx.x;
  if (c >= NDIM) return;
  float iv = 1.f, ov = 1.f;
  #pragma unroll
  for (int i = 0; i < 16; ++i) {
    if (ipos[i] == c) iv *= iscale[i];
    if (opos[i] == c) ov *= oscale[i];
  }
  icm[c] = iv; ocm[c] = ov;
}

// ---------------- step 0: h1 = norm(tanh(B + x*icm)) ----------------
__global__ __launch_bounds__(512) void step0_kernel(
    const float* __restrict__ x, const float* __restrict__ bias,
    const float* __restrict__ icm, const float* __restrict__ nw,
    const float* __restrict__ ocm,
    unsigned short* __restrict__ hbuf, float* __restrict__ out) {
  int row = blockIdx.x;
  int tid = threadIdx.x;
  const float* xr = x + (size_t)row * NDIM;
  float a[8];
  float sq = 0.f;
  #pragma unroll
  for (int p = 0; p < 2; ++p) {
    int c = p * 2048 + tid * 4;
    f32x4 xv = *(const f32x4*)(xr + c);
    f32x4 bv = *(const f32x4*)(bias + c);
    f32x4 ic = *(const f32x4*)(icm + c);
    #pragma unroll
    for (int j = 0; j < 4; ++j) {
      float av = tanhf(bv[j] + xv[j] * ic[j]);
      a[p * 4 + j] = av;
      sq += av * av;
    }
  }
  float tot = block_reduce_sum_512(sq);
  float scale = rsqrtf(tot * (1.0f / NDIM) + EPS_RMS);
  unsigned short* hrow = hbuf + (size_t)row * NDIM;
  float* orow = out + (size_t)row * STEPS * NDIM;  // t = 0
  #pragma unroll
  for (int p = 0; p < 2; ++p) {
    int c = p * 2048 + tid * 4;
    f32x4 nv = *(const f32x4*)(nw + c);
    f32x4 oc = *(const f32x4*)(ocm + c);
    u16x4 hs; f32x4 os;
    #pragma unroll
    for (int j = 0; j < 4; ++j) {
      float h = a[p * 4 + j] * scale * nv[j];
      hs[j] = f2h(h);
      os[j] = h * oc[j];
    }
    *(u16x4*)(hrow + c) = hs;
    *(f32x4*)(orow + c) = os;
  }
}

// ---------------- GEMM: pbuf[ks] = (h @ W)[128x128 tile, K-slice], fp16 out ----
// grid (32 n, 2 m, ksplit) -> 1024 blocks at ksplit=16 = 4 blocks/CU (16 waves).
// BK=32, LDS 32KB/block (2 buf x (128+128)x32 fp16). Wave-tile 64x64.
// VGPR capped at 128 via __launch_bounds__(256,4).
__global__ __launch_bounds__(256, 4) void gemm_kernel(
    const unsigned short* __restrict__ A,   // h fp16 [256][4096]
    const unsigned short* __restrict__ Bt,  // Wt fp16 [n][k]
    unsigned short* __restrict__ pbuf,      // [ksplit][256][4096] fp16
    int kslen) {
  __shared__ __align__(16) unsigned short As[2][128 * 32];
  __shared__ __align__(16) unsigned short Bs[2][128 * 32];
  const int tid = threadIdx.x;
  const int n0 = blockIdx.x * 128;
  const int m0 = blockIdx.y * 128;
  const int ks = blockIdx.z;
  const int kbase = ks * kslen;
  const int nit = kslen >> 5;            // BK=32 iterations
  const int wave = tid >> 6, lane = tid & 63;
  const int wm = (wave >> 1) * 64, wn = (wave & 1) * 64;
  const int l15 = lane & 15;
  const int g = lane >> 4;               // 0..3 k-chunk group of fragment
  // staging decode: thread -> (row = tid>>2 in 64-row batch, chunk = tid&3)
  const int srow = tid >> 2;
  const int sch = tid & 3;
  const int ksw = (sch ^ (srow & 3)) * 8;   // involution-swizzled k offset (elems)

  const unsigned short* aS0 = A  + (size_t)(m0 + srow) * NDIM + kbase + ksw;
  const unsigned short* aS1 = aS0 + (size_t)64 * NDIM;
  const unsigned short* bS0 = Bt + (size_t)(n0 + srow) * NDIM + kbase + ksw;
  const unsigned short* bS1 = bS0 + (size_t)64 * NDIM;
  const int ldb = wave * 512;            // per-wave LDS dest base (elems)

  f32x4 acc[4][4];
  f32x4 zero = {0.f, 0.f, 0.f, 0.f};
  #pragma unroll
  for (int i = 0; i < 4; ++i)
    #pragma unroll
    for (int j = 0; j < 4; ++j) acc[i][j] = zero;

  // read-side swizzle: chunk_in_lds = g ^ (row&3); row&3 == l15&3 for all frags
  const int rsw = (g ^ (l15 & 3)) * 8;

  // prologue: stage k-tile 0 into buffer 0
  GLDS16(aS0, &As[0][ldb]);
  GLDS16(aS1, &As[0][2048 + ldb]);
  GLDS16(bS0, &Bs[0][ldb]);
  GLDS16(bS1, &Bs[0][2048 + ldb]);

  for (int it = 0; it < nit; ++it) {
    const int p = it & 1;
    SBAR();   // all waves done reading buf[1-p]
    if (it < nit - 1) {
      const int kb = (it + 1) * 32;
      GLDS16(aS0 + kb, &As[1 - p][ldb]);
      GLDS16(aS1 + kb, &As[1 - p][2048 + ldb]);
      GLDS16(bS0 + kb, &Bs[1 - p][ldb]);
      GLDS16(bS1 + kb, &Bs[1 - p][2048 + ldb]);
      asm volatile("s_waitcnt vmcnt(4)" ::: "memory");  // tile `it` landed
    } else {
      asm volatile("s_waitcnt vmcnt(0)" ::: "memory");
    }
    SBAR();   // tile `it` visible to all waves
    f16x8 af[4], bfr[4];
    #pragma unroll
    for (int mf = 0; mf < 4; ++mf)
      af[mf] = *(const f16x8*)&As[p][(wm + mf * 16 + l15) * 32 + rsw];
    #pragma unroll
    for (int nf = 0; nf < 4; ++nf)
      bfr[nf] = *(const f16x8*)&Bs[p][(wn + nf * 16 + l15) * 32 + rsw];
    #pragma unroll
    for (int mf = 0; mf < 4; ++mf)
      #pragma unroll
      for (int nf = 0; nf < 4; ++nf)
        acc[mf][nf] = __builtin_amdgcn_mfma_f32_16x16x32_f16(af[mf], bfr[nf], acc[mf][nf], 0, 0, 0);
  }

  unsigned short* pout = pbuf + (size_t)ks * BATCH * NDIM;
  const int crow = g * 4;
  #pragma unroll
  for (int mf = 0; mf < 4; ++mf) {
    #pragma unroll
    for (int nf = 0; nf < 4; ++nf) {
      int col = n0 + wn + nf * 16 + l15;
      #pragma unroll
      for (int r = 0; r < 4; ++r) {
        int row = m0 + wm + mf * 16 + crow + r;
        pout[(size_t)row * NDIM + col] = f2h(acc[mf][nf][r]);
      }
    }
  }
}

// ---------------- combine fp16 splits + bias + tanh + RMSNorm + outputs --------
__global__ __launch_bounds__(512) void normalize_kernel(
    const unsigned short* __restrict__ pbuf, const float* __restrict__ bias,
    const float* __restrict__ nw, const float* __restrict__ ocm,
    unsigned short* __restrict__ hbuf, float* __restrict__ out,
    float* __restrict__ hfin, int t, int is_last, int ksplit) {
  const size_t SL = (size_t)BATCH * NDIM;
  int row = blockIdx.x;
  int tid = threadIdx.x;
  const unsigned short* p0 = pbuf + (size_t)row * NDIM + tid * 8;
  float s[8];
  {
    const float* b0 = bias + tid * 8;
    #pragma unroll
    for (int j = 0; j < 8; ++j) s[j] = b0[j];
  }
  for (int k = 0; k < ksplit; ++k) {
    u16x8 v = *(const u16x8*)(p0 + (size_t)k * SL);
    #pragma unroll
    for (int j = 0; j < 8; ++j) s[j] += h2f(v[j]);
  }
  float a[8];
  float sq = 0.f;
  #pragma unroll
  for (int j = 0; j < 8; ++j) {
    float av = tanhf(s[j]);
    a[j] = av;
    sq += av * av;
  }
  float tot = block_reduce_sum_512(sq);
  float scale = rsqrtf(tot * (1.0f / NDIM) + EPS_RMS);
  int c = tid * 8;
  unsigned short* hrow = hbuf + (size_t)row * NDIM + c;
  float* orow = out + ((size_t)row * STEPS + t) * NDIM + c;
  const float* nv = nw + c;
  const float* oc = ocm + c;
  u16x8 hs;
  #pragma unroll
  for (int j = 0; j < 8; ++j) {
    float h = a[j] * scale * nv[j];
    hs[j] = f2h(h);
    orow[j] = h * oc[j];
    if (is_last) hfin[(size_t)row * NDIM + c + j] = h;
  }
  *(u16x8*)hrow = hs;
}

extern "C" void kernel_launch(void* const* d_in, const int* in_sizes, int n_in,
                              void* d_out, int out_size, void* d_ws, size_t ws_size,
                              hipStream_t stream) {
  (void)in_sizes; (void)n_in; (void)out_size;
  const float* x      = (const float*)d_in[0];
  const float* W      = (const float*)d_in[1];
  const float* Bb     = (const float*)d_in[2];
  const float* iscale = (const float*)d_in[3];
  const float* oscale = (const float*)d_in[4];
  const float* nw     = (const float*)d_in[5];
  const int* ipos = (const int*)d_in[6];
  const int* opos = (const int*)d_in[7];
  // d_in[8] = steps (fixed at 16 by the problem spec).

  char* ws = (char*)d_ws;
  unsigned short* Wt   = (unsigned short*)(ws);             // 32 MiB fp16
  unsigned short* hbuf = (unsigned short*)(ws + 33554432);  // 2 MiB fp16
  float* icm           = (float*)(ws + 35651584);           // 16 KiB
  float* ocm           = (float*)(ws + 35667968);           // 16 KiB
  unsigned short* pbuf = (unsigned short*)(ws + 35684352);  // up to 32 MiB fp16

  // ksplit16 needs ~69 MiB total; fall back to 8 (53 MiB) if ws is tight.
  size_t need16 = 35684352 + (size_t)16 * BATCH * NDIM * sizeof(unsigned short);
  int ksplit = (ws_size >= need16) ? 16 : 8;
  int kslen = NDIM / ksplit;

  float* out  = (float*)d_out;
  float* hfin = out + (size_t)BATCH * STEPS * NDIM;

  hipLaunchKernelGGL(transpose_w, dim3(64, 64), dim3(256), 0, stream, W, Wt);
  hipLaunchKernelGGL(init_colmul, dim3(16), dim3(256), 0, stream,
                     iscale, oscale, ipos, opos, icm, ocm);
  hipLaunchKernelGGL(step0_kernel, dim3(256), dim3(512), 0, stream,
                     x, Bb, icm, nw, ocm, hbuf, out);
  for (int t = 1; t < STEPS; ++t) {
    hipLaunchKernelGGL(gemm_kernel, dim3(32, 2, ksplit), dim3(256), 0, stream,
                       hbuf, Wt, pbuf, kslen);
    hipLaunchKernelGGL(normalize_kernel, dim3(256), dim3(512), 0, stream,
                       pbuf, Bb, nw, ocm, hbuf, out, hfin, t,
                       (t == STEPS - 1) ? 1 : 0, ksplit);
  }
}

// Round 9
// 373.299 us; speedup vs baseline: 1.3885x; 1.3885x over previous
//
#include <hip/hip_runtime.h>
#include <hip/hip_bf16.h>

#define BATCH 256
#define NDIM  4096
#define STEPS 16
#define EPS_RMS 1.1920929e-07f

typedef _Float16 f16x8 __attribute__((ext_vector_type(8)));
typedef float  f32x4  __attribute__((ext_vector_type(4)));
typedef unsigned short u16x4 __attribute__((ext_vector_type(4)));
typedef unsigned int   u32x4 __attribute__((ext_vector_type(4)));

#define AS1 __attribute__((address_space(1)))
#define AS3 __attribute__((address_space(3)))
#define GLDS16(gp, lp) __builtin_amdgcn_global_load_lds( \
    (const AS1 void*)(gp), (AS3 void*)(lp), 16, 0, 0)
#define SBAR() do { asm volatile("" ::: "memory"); \
                    __builtin_amdgcn_s_barrier();  \
                    asm volatile("" ::: "memory"); } while (0)

__device__ __forceinline__ unsigned short f2h(float f) {
  _Float16 h = (_Float16)f;
  union { _Float16 h; unsigned short u; } v; v.h = h; return v.u;
}

__device__ __forceinline__ float block_reduce_sum_512(float v) {
  __shared__ float ws[8];
  __shared__ float tot;
  #pragma unroll
  for (int off = 32; off > 0; off >>= 1) v += __shfl_down(v, off, 64);
  int lane = threadIdx.x & 63, w = threadIdx.x >> 6;
  if (lane == 0) ws[w] = v;
  __syncthreads();
  if (threadIdx.x == 0) {
    float t = 0.f;
    #pragma unroll
    for (int i = 0; i < 8; ++i) t += ws[i];
    tot = t;
  }
  __syncthreads();
  return tot;
}

// ------- W (f32, [k][n]) -> Wt (fp16, [n][k]); blocks y==0 also fill icm/ocm -------
__global__ __launch_bounds__(256) void transpose_w(
    const float* __restrict__ W, unsigned short* __restrict__ Wt,
    const float* __restrict__ iscale, const float* __restrict__ oscale,
    const int* __restrict__ ipos, const int* __restrict__ opos,
    float* __restrict__ icm, float* __restrict__ ocm) {
  __shared__ float tile[64][65];
  int n0 = blockIdx.x * 64;
  int k0 = blockIdx.y * 64;
  int t = threadIdx.x;
  if (blockIdx.y == 0 && t < 64) {
    int c = n0 + t;
    float iv = 1.f, ov = 1.f;
    #pragma unroll
    for (int i = 0; i < 16; ++i) {
      if (ipos[i] == c) iv *= iscale[i];
      if (opos[i] == c) ov *= oscale[i];
    }
    icm[c] = iv; ocm[c] = ov;
  }
  int r = t >> 4, c4 = (t & 15) * 4;
  #pragma unroll
  for (int p = 0; p < 4; ++p) {
    f32x4 v = *(const f32x4*)(W + (size_t)(k0 + r + 16 * p) * NDIM + n0 + c4);
    tile[r + 16 * p][c4 + 0] = v[0];
    tile[r + 16 * p][c4 + 1] = v[1];
    tile[r + 16 * p][c4 + 2] = v[2];
    tile[r + 16 * p][c4 + 3] = v[3];
  }
  __syncthreads();
  #pragma unroll
  for (int p = 0; p < 4; ++p) {
    int nr = r + 16 * p;
    u16x4 o;
    #pragma unroll
    for (int j = 0; j < 4; ++j) o[j] = f2h(tile[c4 + j][nr]);
    *(u16x4*)(Wt + (size_t)(n0 + nr) * NDIM + k0 + c4) = o;
  }
}

// ---------------- step 0: h1 = norm(tanh(B + x*icm)) ----------------
__global__ __launch_bounds__(512) void step0_kernel(
    const float* __restrict__ x, const float* __restrict__ bias,
    const float* __restrict__ icm, const float* __restrict__ nw,
    const float* __restrict__ ocm,
    unsigned short* __restrict__ hbuf, float* __restrict__ out) {
  int row = blockIdx.x;
  int tid = threadIdx.x;
  const float* xr = x + (size_t)row * NDIM;
  float a[8];
  float sq = 0.f;
  #pragma unroll
  for (int p = 0; p < 2; ++p) {
    int c = p * 2048 + tid * 4;
    f32x4 xv = *(const f32x4*)(xr + c);
    f32x4 bv = *(const f32x4*)(bias + c);
    f32x4 ic = *(const f32x4*)(icm + c);
    #pragma unroll
    for (int j = 0; j < 4; ++j) {
      float av = tanhf(bv[j] + xv[j] * ic[j]);
      a[p * 4 + j] = av;
      sq += av * av;
    }
  }
  float tot = block_reduce_sum_512(sq);
  float scale = rsqrtf(tot * (1.0f / NDIM) + EPS_RMS);
  unsigned short* hrow = hbuf + (size_t)row * NDIM;
  float* orow = out + (size_t)row * STEPS * NDIM;  // t = 0
  #pragma unroll
  for (int p = 0; p < 2; ++p) {
    int c = p * 2048 + tid * 4;
    f32x4 nv = *(const f32x4*)(nw + c);
    f32x4 oc = *(const f32x4*)(ocm + c);
    u16x4 hs; f32x4 os;
    #pragma unroll
    for (int j = 0; j < 4; ++j) {
      float h = a[p * 4 + j] * scale * nv[j];
      hs[j] = f2h(h);
      os[j] = h * oc[j];
    }
    *(u16x4*)(hrow + c) = hs;
    *(f32x4*)(orow + c) = os;
  }
}

// ---------------- GEMM: pbuf[ks] = (h @ W)[64x128 tile, K-slice 1024] ----------------
// grid (32, 4, 4) = 512 blocks (2/CU, 8 waves/CU), 256 threads (4 waves, 2x2).
// Triple-buffered LDS (72KB), ONE s_barrier per K-iter, counted vmcnt(12):
// two k-tiles of global_load_lds stay in flight across barriers.
__global__ __launch_bounds__(256, 2) void gemm_kernel(
    const unsigned short* __restrict__ A,   // h fp16 [256][4096]
    const unsigned short* __restrict__ Bt,  // Wt fp16 [n][k]
    float* __restrict__ pbuf) {             // [4][256][4096] f32
  __shared__ __align__(16) unsigned short As[3][64 * 64];    // 24 KB
  __shared__ __align__(16) unsigned short Bs[3][128 * 64];   // 48 KB
  const int tid = threadIdx.x;
  const int n0 = blockIdx.x * 128;
  const int m0 = blockIdx.y * 64;
  const int ks = blockIdx.z;
  const int kbase = ks * 1024;
  const int wave = tid >> 6, lane = tid & 63;
  const int wm = (wave >> 1) * 32, wn = (wave & 1) * 64;
  const int l15 = lane & 15;
  const int g = lane >> 4;               // 0..3 (K-group of fragment)
  const int q = l15 & 7;                 // row&7 for swizzle on read side
  const int rho = lane >> 3;             // 0..7 staging row within 8-row issue
  const int koff = ((lane & 7) ^ rho) * 8;  // swizzled K-chunk (elems)

  const unsigned short* aP[2];
  const unsigned short* bP[4];
  #pragma unroll
  for (int i = 0; i < 2; ++i)
    aP[i] = A + (size_t)(m0 + wave * 16 + i * 8 + rho) * NDIM + kbase + koff;
  #pragma unroll
  for (int i = 0; i < 4; ++i)
    bP[i] = Bt + (size_t)(n0 + wave * 32 + i * 8 + rho) * NDIM + kbase + koff;

  f32x4 acc[2][4];
  f32x4 zero = {0.f, 0.f, 0.f, 0.f};
  #pragma unroll
  for (int i = 0; i < 2; ++i)
    #pragma unroll
    for (int j = 0; j < 4; ++j) acc[i][j] = zero;

  // prologue: stage k-tiles 0 and 1 into buffers 0 and 1 (12 loads in flight)
  #pragma unroll
  for (int b = 0; b < 2; ++b) {
    #pragma unroll
    for (int i = 0; i < 2; ++i)
      GLDS16(aP[i] + b * 64, &As[b][(wave * 16 + i * 8) * 64]);
    #pragma unroll
    for (int i = 0; i < 4; ++i)
      GLDS16(bP[i] + b * 64, &Bs[b][(wave * 32 + i * 8) * 64]);
  }

  int pr = 0, pw = 2;   // read buffer, write buffer (mod-3 counters)
  for (int it = 0; it < 16; ++it) {
    SBAR();   // all waves done reading buf[pw] (= iter it-1's read buffer + 3)
    if (it < 14) {
      const int kb = (it + 2) * 64;
      #pragma unroll
      for (int i = 0; i < 2; ++i)
        GLDS16(aP[i] + kb, &As[pw][(wave * 16 + i * 8) * 64]);
      #pragma unroll
      for (int i = 0; i < 4; ++i)
        GLDS16(bP[i] + kb, &Bs[pw][(wave * 32 + i * 8) * 64]);
      asm volatile("s_waitcnt vmcnt(12)" ::: "memory");  // tile `it` landed
    } else if (it == 14) {
      asm volatile("s_waitcnt vmcnt(6)" ::: "memory");
    } else {
      asm volatile("s_waitcnt vmcnt(0)" ::: "memory");
    }
    #pragma unroll
    for (int kk = 0; kk < 2; ++kk) {
      f16x8 af[2], bfr[4];
      #pragma unroll
      for (int mf = 0; mf < 2; ++mf) {
        int row = wm + mf * 16 + l15;
        af[mf] = *(const f16x8*)&As[pr][row * 64 + (((kk << 2) + g) ^ q) * 8];
      }
      #pragma unroll
      for (int nf = 0; nf < 4; ++nf) {
        int row = wn + nf * 16 + l15;
        bfr[nf] = *(const f16x8*)&Bs[pr][row * 64 + (((kk << 2) + g) ^ q) * 8];
      }
      #pragma unroll
      for (int mf = 0; mf < 2; ++mf)
        #pragma unroll
        for (int nf = 0; nf < 4; ++nf)
          acc[mf][nf] = __builtin_amdgcn_mfma_f32_16x16x32_f16(af[mf], bfr[nf], acc[mf][nf], 0, 0, 0);
    }
    pr = (pr == 2) ? 0 : pr + 1;
    pw = (pw == 2) ? 0 : pw + 1;
  }

  float* pout = pbuf + (size_t)ks * BATCH * NDIM;
  const int crow = (lane >> 4) * 4;
  #pragma unroll
  for (int mf = 0; mf < 2; ++mf) {
    #pragma unroll
    for (int nf = 0; nf < 4; ++nf) {
      int col = n0 + wn + nf * 16 + l15;
      #pragma unroll
      for (int r = 0; r < 4; ++r) {
        int row = m0 + wm + mf * 16 + crow + r;
        pout[(size_t)row * NDIM + col] = acc[mf][nf][r];
      }
    }
  }
}

// ---------------- combine splits + bias + tanh + RMSNorm + outputs ----------------
__global__ __launch_bounds__(512) void normalize_kernel(
    const float* __restrict__ pbuf, const float* __restrict__ bias,
    const float* __restrict__ nw, const float* __restrict__ ocm,
    unsigned short* __restrict__ hbuf, float* __restrict__ out,
    float* __restrict__ hfin, int t, int is_last) {
  const size_t SL = (size_t)BATCH * NDIM;
  int row = blockIdx.x;
  int tid = threadIdx.x;
  const float* p0 = pbuf + (size_t)row * NDIM;
  float a[8];
  float sq = 0.f;
  #pragma unroll
  for (int p = 0; p < 2; ++p) {
    int c = p * 2048 + tid * 4;
    f32x4 s = *(const f32x4*)(p0 + c);
    s += *(const f32x4*)(p0 + SL + c);
    s += *(const f32x4*)(p0 + 2 * SL + c);
    s += *(const f32x4*)(p0 + 3 * SL + c);
    f32x4 bv = *(const f32x4*)(bias + c);
    #pragma unroll
    for (int j = 0; j < 4; ++j) {
      float av = tanhf(s[j] + bv[j]);
      a[p * 4 + j] = av;
      sq += av * av;
    }
  }
  float tot = block_reduce_sum_512(sq);
  float scale = rsqrtf(tot * (1.0f / NDIM) + EPS_RMS);
  unsigned short* hrow = hbuf + (size_t)row * NDIM;
  float* orow = out + ((size_t)row * STEPS + t) * NDIM;
  #pragma unroll
  for (int p = 0; p < 2; ++p) {
    int c = p * 2048 + tid * 4;
    f32x4 nv = *(const f32x4*)(nw + c);
    f32x4 oc = *(const f32x4*)(ocm + c);
    u16x4 hs; f32x4 os; f32x4 hv;
    #pragma unroll
    for (int j = 0; j < 4; ++j) {
      float h = a[p * 4 + j] * scale * nv[j];
      hv[j] = h;
      hs[j] = f2h(h);
      os[j] = h * oc[j];
    }
    *(u16x4*)(hrow + c) = hs;
    *(f32x4*)(orow + c) = os;
    if (is_last) *(f32x4*)(hfin + (size_t)row * NDIM + c) = hv;
  }
}

extern "C" void kernel_launch(void* const* d_in, const int* in_sizes, int n_in,
                              void* d_out, int out_size, void* d_ws, size_t ws_size,
                              hipStream_t stream) {
  (void)in_sizes; (void)n_in; (void)out_size; (void)ws_size;
  const float* x      = (const float*)d_in[0];
  const float* W      = (const float*)d_in[1];
  const float* Bb     = (const float*)d_in[2];
  const float* iscale = (const float*)d_in[3];
  const float* oscale = (const float*)d_in[4];
  const float* nw     = (const float*)d_in[5];
  const int* ipos = (const int*)d_in[6];
  const int* opos = (const int*)d_in[7];
  // d_in[8] = steps (fixed at 16 by the problem spec).

  char* ws = (char*)d_ws;
  unsigned short* Wt   = (unsigned short*)(ws);             // 32 MiB fp16
  unsigned short* hbuf = (unsigned short*)(ws + 33554432);  // 2 MiB fp16
  float* icm           = (float*)(ws + 35651584);           // 16 KiB
  float* ocm           = (float*)(ws + 35667968);           // 16 KiB
  float* pbuf          = (float*)(ws + 35684352);           // 16 MiB (4 slices)

  float* out  = (float*)d_out;
  float* hfin = out + (size_t)BATCH * STEPS * NDIM;

  hipLaunchKernelGGL(transpose_w, dim3(64, 64), dim3(256), 0, stream,
                     W, Wt, iscale, oscale, ipos, opos, icm, ocm);
  hipLaunchKernelGGL(step0_kernel, dim3(256), dim3(512), 0, stream,
                     x, Bb, icm, nw, ocm, hbuf, out);
  for (int t = 1; t < STEPS; ++t) {
    hipLaunchKernelGGL(gemm_kernel, dim3(32, 4, 4), dim3(256), 0, stream,
                       hbuf, Wt, pbuf);
    hipLaunchKernelGGL(normalize_kernel, dim3(256), dim3(512), 0, stream,
                       pbuf, Bb, nw, ocm, hbuf, out, hfin, t, (t == STEPS - 1) ? 1 : 0);
  }
}